// Round 1
// baseline (292.129 us; speedup 1.0000x reference)
//
#include <hip/hip_runtime.h>

typedef _Float16 half8 __attribute__((ext_vector_type(8)));
typedef float floatx4 __attribute__((ext_vector_type(4)));

#define B_   8
#define SE   4096
#define SD   4096
#define D_   128

#define MT   64     // Q rows per block
#define NT   64     // K rows per tile
#define LDK  136    // Ks row stride in halves (128 + 8): 272B, 16B-aligned, 2-way banks
#define LDV  72     // Vts row stride (64 + 8): 144B
#define LDP  72     // P row stride

// ---------- prep 1: q = fp16(h @ W), fp32 accumulate ----------
__global__ __launch_bounds__(256) void qprep(const float* __restrict__ h,
                                             const float* __restrict__ W,
                                             _Float16* __restrict__ q) {
    __shared__ float Ws[128 * 128];   // 64KB? no: 128*128*4 = 64KB... + Hs 32KB  -> split loads below
    __shared__ float Hs[64 * 128];
    const int row0 = blockIdx.x * 64;
    for (int i = threadIdx.x; i < 128 * 128 / 4; i += 256)
        ((float4*)Ws)[i] = ((const float4*)W)[i];
    for (int i = threadIdx.x; i < 64 * 128 / 4; i += 256)
        ((float4*)Hs)[i] = ((const float4*)(h + (size_t)row0 * 128))[i];
    __syncthreads();
    const int tr = threadIdx.x >> 5;   // 0..7 -> rows tr*8 .. tr*8+7
    const int tc = threadIdx.x & 31;   // cols tc + 32*j  (conflict-free LDS banks)
    float acc[8][4];
    #pragma unroll
    for (int i = 0; i < 8; ++i)
        #pragma unroll
        for (int j = 0; j < 4; ++j) acc[i][j] = 0.f;
    for (int d = 0; d < 128; ++d) {
        float wv0 = Ws[d * 128 + tc +  0];
        float wv1 = Ws[d * 128 + tc + 32];
        float wv2 = Ws[d * 128 + tc + 64];
        float wv3 = Ws[d * 128 + tc + 96];
        #pragma unroll
        for (int i = 0; i < 8; ++i) {
            float hv = Hs[(tr * 8 + i) * 128 + d];
            acc[i][0] += hv * wv0; acc[i][1] += hv * wv1;
            acc[i][2] += hv * wv2; acc[i][3] += hv * wv3;
        }
    }
    #pragma unroll
    for (int i = 0; i < 8; ++i)
        #pragma unroll
        for (int j = 0; j < 4; ++j)
            q[((size_t)(row0 + tr * 8 + i)) * 128 + tc + 32 * j] = (_Float16)acc[i][j];
}

// ---------- prep 2: k = fp16(b), vT = fp16(b^T) via LDS tile transpose ----------
__global__ __launch_bounds__(256) void kvprep(const float* __restrict__ b,
                                              _Float16* __restrict__ k,
                                              _Float16* __restrict__ vT) {
    __shared__ float tile[32][33];
    const int s0 = blockIdx.x * 32, d0 = blockIdx.y * 32, bb = blockIdx.z;
    const int tx = threadIdx.x & 31, ty = threadIdx.x >> 5;   // ty 0..7
    for (int r = ty; r < 32; r += 8) {
        float v = b[((size_t)bb * SE + s0 + r) * D_ + d0 + tx];
        tile[r][tx] = v;
        k[((size_t)bb * SE + s0 + r) * D_ + d0 + tx] = (_Float16)v;
    }
    __syncthreads();
    for (int r = ty; r < 32; r += 8)
        vT[((size_t)bb * D_ + d0 + r) * SE + s0 + tx] = (_Float16)tile[tx][r];
}

// ---------- fused flash attention: scores = qk^T, online softmax, O = P vT^T ----------
__global__ __launch_bounds__(256) void flash(const _Float16* __restrict__ q,
                                             const _Float16* __restrict__ k,
                                             const _Float16* __restrict__ vT,
                                             float* __restrict__ out) {
    __shared__ _Float16 Ks[NT * LDK];        // 64 x 128  (17408 B)
    __shared__ _Float16 Vts[D_ * LDV];       // 128 x 64  (18432 B)
    __shared__ _Float16 Ps[4 * 16 * LDP];    // per-wave 16 x 64 (9216 B)  -> 44KB total

    const int bb   = blockIdx.y;
    const int q0   = blockIdx.x * MT;
    const int tid  = threadIdx.x;
    const int wave = tid >> 6;
    const int lane = tid & 63;
    const int l15  = lane & 15;
    const int quad = lane >> 4;

    // Preload this wave's Q A-fragments straight from global (A[m=lane&15][k=quad*8+j])
    const _Float16* qrow = q + ((size_t)bb * SD + q0 + wave * 16 + l15) * D_;
    half8 qf[4];
    #pragma unroll
    for (int ks = 0; ks < 4; ++ks)
        qf[ks] = *(const half8*)(qrow + ks * 32 + quad * 8);

    floatx4 acc_o[8];
    #pragma unroll
    for (int i = 0; i < 8; ++i) acc_o[i] = (floatx4){0.f, 0.f, 0.f, 0.f};
    float mrow[4] = {-1e30f, -1e30f, -1e30f, -1e30f};
    float lrow[4] = {0.f, 0.f, 0.f, 0.f};

    _Float16* Pw = Ps + wave * 16 * LDP;

    for (int t = 0; t < SE / NT; ++t) {
        const int s0 = t * NT;
        __syncthreads();   // previous iter's MFMA reads of Ks/Vts done
        // stage Ks: 64 rows x 16 segs of 16B
        {
            const _Float16* kg = k + ((size_t)bb * SE + s0) * D_;
            #pragma unroll
            for (int it = 0; it < 4; ++it) {
                int idx = tid + it * 256;          // 0..1023
                int row = idx >> 4, seg = idx & 15;
                *(uint4*)(Ks + row * LDK + seg * 8) = *(const uint4*)(kg + row * D_ + seg * 8);
            }
            const _Float16* vg = vT + (size_t)bb * D_ * SE + s0;
            #pragma unroll
            for (int it = 0; it < 4; ++it) {
                int idx = tid + it * 256;          // 0..1023
                int row = idx >> 3, seg = idx & 7;
                *(uint4*)(Vts + row * LDV + seg * 8) = *(const uint4*)(vg + (size_t)row * SE + seg * 8);
            }
        }
        __syncthreads();

        // S = Q K^T : 4 n-tiles of 16, K-dim 128 in 4 steps
        floatx4 accs[4];
        #pragma unroll
        for (int nt = 0; nt < 4; ++nt) accs[nt] = (floatx4){0.f, 0.f, 0.f, 0.f};
        #pragma unroll
        for (int ks = 0; ks < 4; ++ks) {
            #pragma unroll
            for (int nt = 0; nt < 4; ++nt) {
                half8 bf = *(const half8*)(Ks + (nt * 16 + l15) * LDK + ks * 32 + quad * 8);
                accs[nt] = __builtin_amdgcn_mfma_f32_16x16x32_f16(qf[ks], bf, accs[nt], 0, 0, 0);
            }
        }

        // online softmax; C layout: row = quad*4 + r, col = nt*16 + l15
        float alpha[4], rsum[4];
        #pragma unroll
        for (int r = 0; r < 4; ++r) {
            float mv = accs[0][r];
            mv = fmaxf(mv, accs[1][r]); mv = fmaxf(mv, accs[2][r]); mv = fmaxf(mv, accs[3][r]);
            #pragma unroll
            for (int off = 1; off < 16; off <<= 1) mv = fmaxf(mv, __shfl_xor(mv, off, 64));
            float mnew = fmaxf(mrow[r], mv);
            alpha[r] = __expf(mrow[r] - mnew);
            mrow[r] = mnew;
            rsum[r] = 0.f;
        }
        #pragma unroll
        for (int nt = 0; nt < 4; ++nt) {
            #pragma unroll
            for (int r = 0; r < 4; ++r) {
                float p = __expf(accs[nt][r] - mrow[r]);
                rsum[r] += p;
                Pw[(quad * 4 + r) * LDP + nt * 16 + l15] = (_Float16)p;
            }
        }
        #pragma unroll
        for (int r = 0; r < 4; ++r) {
            float s = rsum[r];
            #pragma unroll
            for (int off = 1; off < 16; off <<= 1) s += __shfl_xor(s, off, 64);
            lrow[r] = lrow[r] * alpha[r] + s;
        }
        #pragma unroll
        for (int dt = 0; dt < 8; ++dt)
            #pragma unroll
            for (int r = 0; r < 4; ++r) acc_o[dt][r] *= alpha[r];

        __syncthreads();   // drain own-wave P LDS writes (lgkmcnt) before A-frag reads

        // O += P * V : k-dim 64 in 2 steps, 8 d-tiles
        #pragma unroll
        for (int ks = 0; ks < 2; ++ks) {
            half8 pf = *(const half8*)(Pw + l15 * LDP + ks * 32 + quad * 8);
            #pragma unroll
            for (int dt = 0; dt < 8; ++dt) {
                half8 vf = *(const half8*)(Vts + (dt * 16 + l15) * LDV + ks * 32 + quad * 8);
                acc_o[dt] = __builtin_amdgcn_mfma_f32_16x16x32_f16(pf, vf, acc_o[dt], 0, 0, 0);
            }
        }
    }

    // epilogue: O / l, fp32 out
    float linv[4];
    #pragma unroll
    for (int r = 0; r < 4; ++r) linv[r] = 1.f / lrow[r];
    float* orow = out + ((size_t)bb * SD + q0 + wave * 16) * D_;
    #pragma unroll
    for (int dt = 0; dt < 8; ++dt)
        #pragma unroll
        for (int r = 0; r < 4; ++r)
            orow[(size_t)(quad * 4 + r) * D_ + dt * 16 + l15] = acc_o[dt][r] * linv[r];
}

extern "C" void kernel_launch(void* const* d_in, const int* in_sizes, int n_in,
                              void* d_out, int out_size, void* d_ws, size_t ws_size,
                              hipStream_t stream) {
    const float* b = (const float*)d_in[0];   // [B, SE, D]
    const float* h = (const float*)d_in[1];   // [B, SD, D]
    const float* W = (const float*)d_in[2];   // [D, D]
    float* out = (float*)d_out;               // [B, SD, D] fp32

    _Float16* q  = (_Float16*)d_ws;                 // [B, SD, D] fp16  (8.39 MB)
    _Float16* k  = q + (size_t)B_ * SD * D_;        // [B, SE, D] fp16  (8.39 MB)
    _Float16* vT = k + (size_t)B_ * SE * D_;        // [B, D, SE] fp16  (8.39 MB)

    qprep<<<(B_ * SD) / 64, 256, 0, stream>>>(h, W, q);
    kvprep<<<dim3(SE / 32, D_ / 32, B_), 256, 0, stream>>>(b, k, vT);
    flash<<<dim3(SD / MT, B_), 256, 0, stream>>>(q, k, vT, out);
}

// Round 2
// 262.472 us; speedup vs baseline: 1.1130x; 1.1130x over previous
//
#include <hip/hip_runtime.h>

typedef _Float16 half2v __attribute__((ext_vector_type(2)));
typedef _Float16 half4 __attribute__((ext_vector_type(4)));
typedef _Float16 half8 __attribute__((ext_vector_type(8)));
typedef float floatx4 __attribute__((ext_vector_type(4)));

#define B_   8
#define SE   4096
#define SD   4096
#define D_   128

#define MT   64     // Q rows per block (4 waves x 16)
#define NT   64     // K rows per tile
#define LDK  136    // Ks row stride in halves (128 + 8): 272B, 16B-aligned
#define LDV  72     // Vts row stride (64 + 8): 144B

// ---------- prep 1: q = fp16(h @ W), fp32 accumulate ----------
__global__ __launch_bounds__(256) void qprep(const float* __restrict__ h,
                                             const float* __restrict__ W,
                                             _Float16* __restrict__ q) {
    __shared__ float Ws[128 * 128];
    __shared__ float Hs[64 * 128];
    const int row0 = blockIdx.x * 64;
    for (int i = threadIdx.x; i < 128 * 128 / 4; i += 256)
        ((float4*)Ws)[i] = ((const float4*)W)[i];
    for (int i = threadIdx.x; i < 64 * 128 / 4; i += 256)
        ((float4*)Hs)[i] = ((const float4*)(h + (size_t)row0 * 128))[i];
    __syncthreads();
    const int tr = threadIdx.x >> 5;
    const int tc = threadIdx.x & 31;
    float acc[8][4];
    #pragma unroll
    for (int i = 0; i < 8; ++i)
        #pragma unroll
        for (int j = 0; j < 4; ++j) acc[i][j] = 0.f;
    for (int d = 0; d < 128; ++d) {
        float wv0 = Ws[d * 128 + tc +  0];
        float wv1 = Ws[d * 128 + tc + 32];
        float wv2 = Ws[d * 128 + tc + 64];
        float wv3 = Ws[d * 128 + tc + 96];
        #pragma unroll
        for (int i = 0; i < 8; ++i) {
            float hv = Hs[(tr * 8 + i) * 128 + d];
            acc[i][0] += hv * wv0; acc[i][1] += hv * wv1;
            acc[i][2] += hv * wv2; acc[i][3] += hv * wv3;
        }
    }
    #pragma unroll
    for (int i = 0; i < 8; ++i)
        #pragma unroll
        for (int j = 0; j < 4; ++j)
            q[((size_t)(row0 + tr * 8 + i)) * 128 + tc + 32 * j] = (_Float16)acc[i][j];
}

// ---------- prep 2: k = fp16(b), vT = fp16(b^T), half2-packed stores ----------
__global__ __launch_bounds__(256) void kvprep(const float* __restrict__ b,
                                              _Float16* __restrict__ k,
                                              _Float16* __restrict__ vT) {
    __shared__ float tile[32][33];
    const int s0 = blockIdx.x * 32, d0 = blockIdx.y * 32, bb = blockIdx.z;
    const int tid = threadIdx.x;
    const int dp = tid & 15;     // d-pair index: d = 2*dp
    const int r0 = tid >> 4;     // 0..15
    #pragma unroll
    for (int r = r0; r < 32; r += 16) {
        float2 v = *(const float2*)(b + ((size_t)bb * SE + s0 + r) * D_ + d0 + 2 * dp);
        tile[r][2 * dp] = v.x; tile[r][2 * dp + 1] = v.y;
        half2v hv = { (_Float16)v.x, (_Float16)v.y };
        *(half2v*)(k + ((size_t)bb * SE + s0 + r) * D_ + d0 + 2 * dp) = hv;
    }
    __syncthreads();
    const int sp = tid & 15;     // s-pair: s = 2*sp
    const int dr0 = tid >> 4;
    #pragma unroll
    for (int dr = dr0; dr < 32; dr += 16) {
        half2v w = { (_Float16)tile[2 * sp][dr], (_Float16)tile[2 * sp + 1][dr] };
        *(half2v*)(vT + ((size_t)bb * D_ + d0 + dr) * SE + s0 + 2 * sp) = w;
    }
}

// ---------- fused flash attention: S^T = K Q^T (16x16x32), P chained in
// registers into O += P V (16x16x16) -- no P LDS round-trip ----------
__global__ __launch_bounds__(256) void flash(const _Float16* __restrict__ q,
                                             const _Float16* __restrict__ k,
                                             const _Float16* __restrict__ vT,
                                             float* __restrict__ out) {
    __shared__ _Float16 Ks[NT * LDK];        // 64 x 128  (17408 B)
    __shared__ _Float16 Vts[D_ * LDV];       // 128 x 64  (18432 B) -> 35840 B total

    const int bb   = blockIdx.y;
    const int q0   = blockIdx.x * MT;
    const int tid  = threadIdx.x;
    const int wave = tid >> 6;
    const int lane = tid & 63;
    const int l15  = lane & 15;
    const int quad = lane >> 4;

    // Q as B-operand fragments: B[n=q=l15][k=d=quad*8+j]
    const _Float16* qrow = q + ((size_t)bb * SD + q0 + wave * 16 + l15) * D_;
    half8 qf[4];
    #pragma unroll
    for (int ks = 0; ks < 4; ++ks)
        qf[ks] = *(const half8*)(qrow + ks * 32 + quad * 8);

    floatx4 acc_o[8];
    #pragma unroll
    for (int i = 0; i < 8; ++i) acc_o[i] = (floatx4){0.f, 0.f, 0.f, 0.f};
    float m_q = -1e30f, l_q = 0.f;

    const _Float16* kbase = k + (size_t)bb * SE * D_;
    const _Float16* vbase = vT + (size_t)bb * D_ * SE;

    for (int t = 0; t < SE / NT; ++t) {
        const int s0 = t * NT;
        __syncthreads();   // previous iter's MFMA reads of Ks/Vts done
        {
            const _Float16* kg = kbase + (size_t)s0 * D_;
            #pragma unroll
            for (int it = 0; it < 4; ++it) {
                int idx = tid + it * 256;          // 0..1023
                int row = idx >> 4, seg = idx & 15;
                *(uint4*)(Ks + row * LDK + seg * 8) = *(const uint4*)(kg + row * D_ + seg * 8);
            }
            const _Float16* vg = vbase + s0;
            #pragma unroll
            for (int it = 0; it < 4; ++it) {
                int idx = tid + it * 256;          // 0..1023
                int row = idx >> 3, seg = idx & 7;
                *(uint4*)(Vts + row * LDV + seg * 8) = *(const uint4*)(vg + (size_t)row * SE + seg * 8);
            }
        }
        __syncthreads();

        // S^T = K Q^T : A = K rows (m=s), B = Q (n=q). C: row=s_local=quad*4+r, col=q=l15
        floatx4 accs[4];
        #pragma unroll
        for (int st = 0; st < 4; ++st) accs[st] = (floatx4){0.f, 0.f, 0.f, 0.f};
        #pragma unroll
        for (int ks = 0; ks < 4; ++ks) {
            #pragma unroll
            for (int st = 0; st < 4; ++st) {
                half8 af = *(const half8*)(Ks + (st * 16 + l15) * LDK + ks * 32 + quad * 8);
                accs[st] = __builtin_amdgcn_mfma_f32_16x16x32_f16(af, qf[ks], accs[st], 0, 0, 0);
            }
        }

        // online softmax over s for column q = l15 (16 in-lane values + cross-quad)
        float mv = accs[0][0];
        #pragma unroll
        for (int st = 0; st < 4; ++st)
            #pragma unroll
            for (int r = 0; r < 4; ++r) mv = fmaxf(mv, accs[st][r]);
        mv = fmaxf(mv, __shfl_xor(mv, 16, 64));
        mv = fmaxf(mv, __shfl_xor(mv, 32, 64));
        float mnew = fmaxf(m_q, mv);
        float alpha = __expf(m_q - mnew);
        m_q = mnew;

        // P = exp(S^T - m), kept in registers: pf[st] IS the A-fragment of PV
        half4 pf[4];
        float psum = 0.f;
        #pragma unroll
        for (int st = 0; st < 4; ++st)
            #pragma unroll
            for (int r = 0; r < 4; ++r) {
                float p = __expf(accs[st][r] - mnew);
                psum += p;
                pf[st][r] = (_Float16)p;
            }
        psum += __shfl_xor(psum, 16, 64);
        psum += __shfl_xor(psum, 32, 64);
        l_q = l_q * alpha + psum;

        // rescale O (rows q = quad*4+r; alpha lives at lane q=l15 -> broadcast)
        float alpha_b[4];
        #pragma unroll
        for (int r = 0; r < 4; ++r) alpha_b[r] = __shfl(alpha, quad * 4 + r, 64);
        #pragma unroll
        for (int dt = 0; dt < 8; ++dt)
            #pragma unroll
            for (int r = 0; r < 4; ++r) acc_o[dt][r] *= alpha_b[r];

        // O += P V : A = pf[st] (regs), B = Vts fragment (b64 read)
        #pragma unroll
        for (int st = 0; st < 4; ++st) {
            #pragma unroll
            for (int dt = 0; dt < 8; ++dt) {
                half4 vf = *(const half4*)(Vts + (dt * 16 + l15) * LDV + st * 16 + quad * 4);
                acc_o[dt] = __builtin_amdgcn_mfma_f32_16x16x16f16(pf[st], vf, acc_o[dt], 0, 0, 0);
            }
        }
    }

    // epilogue: O / l  (O rows q = quad*4+r)
    float linv = 1.f / l_q;
    float linv_b[4];
    #pragma unroll
    for (int r = 0; r < 4; ++r) linv_b[r] = __shfl(linv, quad * 4 + r, 64);
    float* orow = out + ((size_t)bb * SD + q0 + wave * 16) * D_;
    #pragma unroll
    for (int dt = 0; dt < 8; ++dt)
        #pragma unroll
        for (int r = 0; r < 4; ++r)
            orow[(size_t)(quad * 4 + r) * D_ + dt * 16 + l15] = acc_o[dt][r] * linv_b[r];
}

extern "C" void kernel_launch(void* const* d_in, const int* in_sizes, int n_in,
                              void* d_out, int out_size, void* d_ws, size_t ws_size,
                              hipStream_t stream) {
    const float* b = (const float*)d_in[0];   // [B, SE, D]
    const float* h = (const float*)d_in[1];   // [B, SD, D]
    const float* W = (const float*)d_in[2];   // [D, D]
    float* out = (float*)d_out;               // [B, SD, D] fp32

    _Float16* q  = (_Float16*)d_ws;                 // [B, SD, D] fp16
    _Float16* k  = q + (size_t)B_ * SD * D_;        // [B, SE, D] fp16
    _Float16* vT = k + (size_t)B_ * SE * D_;        // [B, D, SE] fp16

    qprep<<<(B_ * SD) / 64, 256, 0, stream>>>(h, W, q);
    kvprep<<<dim3(SE / 32, D_ / 32, B_), 256, 0, stream>>>(b, k, vT);
    flash<<<dim3(SD / MT, B_), 256, 0, stream>>>(q, k, vT, out);
}